// Round 2
// 449.168 us; speedup vs baseline: 1.5451x; 1.5451x over previous
//
#include <hip/hip_runtime.h>

typedef unsigned short u16;
typedef unsigned int u32;
typedef __attribute__((ext_vector_type(8))) short bfrag;     // 8 bf16 (4 VGPRs) MFMA A/B
typedef __attribute__((ext_vector_type(4))) float ffrag;     // 4 f32 MFMA C/D
typedef __attribute__((ext_vector_type(4))) float f4;
typedef __attribute__((ext_vector_type(2))) float f2;        // clang vector: ok for nontemporal builtins
typedef __attribute__((ext_vector_type(4))) int i4;

#define NVERT 35709
#define NFACE 70789
#define NV3   107127
#define NB    128

// ---- workspace byte layout ----
// Batch-minor transposed internal layouts: bt8 = b>>3 (16 slabs), bi = b&7 innermost.
#define SHAPE_OFF 0ull            // f32 shpT[bt8][j][bi]  (54,849,024 B)  j = v*3+c
#define TEX_OFF   54849024ull     // u16 bf16 texT[bt8][j][bi] (27,424,512 B)
#define FXY_OFF   82273536ull     // u32 fn xy (f16,f16) [bt8][f][bi] (36,243,968 B)
#define FZ_OFF    118517504ull    // u16 fn z  (f16)     [bt8][f][bi] (18,121,984 B)
#define CPACK_OFF 154761472ull    // u16 bf16, NB*256 padded coeffs [id80|0*16|ex64|tex80|0*16]
#define ROT_OFF   154827008ull    // f32, NB*9  (M[d][c], M = Rz@Ry@Rx)
#define G_OFF     154831616ull    // f32, NB*27 (G[c][d] = gamma[d*9+c] + 0.8*(c==0))
#define TRANS_OFF 154845440ull    // f32, NB*3
#define MEAN_OFF  154846976ull    // f32, 3
#define PART_OFF  154847040ull    // f32, 64*3 partial sums for mean

// ---- output element offsets (f32 out) ----
#define LMS_BASE  13712256ull     // after face_color (B*NV*3)
#define ST_BASE   13729664ull     // after lms (B*68*2)

__device__ __forceinline__ float b2f(u16 s) {
  union { unsigned u; float f; } v; v.u = ((unsigned)s) << 16; return v.f;
}
__device__ __forceinline__ u16 f2b(float x) {  // f32 -> bf16 RNE
  union { float f; unsigned u; } v; v.f = x;
  unsigned r = v.u + 0x7FFFu + ((v.u >> 16) & 1u);
  return (u16)(r >> 16);
}
__device__ __forceinline__ u16 h2b(float x) {  // f32 -> f16 bits
  union { _Float16 h; u16 u; } v; v.h = (_Float16)x; return v.u;
}
__device__ __forceinline__ float hb2f(u16 u) { // f16 bits -> f32
  union { _Float16 h; u16 u2; } v; v.u2 = u; return (float)v.h;
}
__device__ __forceinline__ bfrag cvt8nt(const float* p) {  // 8 f32 (nt) -> 8 bf16
  f4 a = __builtin_nontemporal_load((const f4*)p);
  f4 b = __builtin_nontemporal_load((const f4*)(p + 4));
  bfrag r;
  r[0] = (short)f2b(a.x); r[1] = (short)f2b(a.y); r[2] = (short)f2b(a.z); r[3] = (short)f2b(a.w);
  r[4] = (short)f2b(b.x); r[5] = (short)f2b(b.y); r[6] = (short)f2b(b.z); r[7] = (short)f2b(b.w);
  return r;
}

// K0: partial sums of meanshape over vertices (64 blocks x 3 comps)
__global__ __launch_bounds__(256) void k_mean(const float* __restrict__ ms, float* __restrict__ part) {
  __shared__ float s[3];
  if (threadIdx.x < 3) s[threadIdx.x] = 0.f;
  __syncthreads();
  float a0 = 0.f, a1 = 0.f, a2 = 0.f;
  for (int v = blockIdx.x * 256 + threadIdx.x; v < NVERT; v += 64 * 256) {
    a0 += ms[v * 3 + 0];
    a1 += ms[v * 3 + 1];
    a2 += ms[v * 3 + 2];
  }
  atomicAdd(&s[0], a0); atomicAdd(&s[1], a1); atomicAdd(&s[2], a2);
  __syncthreads();
  if (threadIdx.x < 3) part[blockIdx.x * 3 + threadIdx.x] = s[threadIdx.x];
}

// K1: finalize mean; per-batch params
__global__ __launch_bounds__(128) void k_params(const float* __restrict__ coeff, u16* __restrict__ cpack,
                                                float* __restrict__ rot, float* __restrict__ G,
                                                float* __restrict__ tr, const float* __restrict__ part,
                                                float* __restrict__ mean) {
  int b = threadIdx.x;
  if (b < 3) {
    float s = 0.f;
    for (int i = 0; i < 64; i++) s += part[i * 3 + b];
    mean[b] = s * (1.0f / (float)NVERT);
  }
  const float* c = coeff + b * 257;
  u16* cp = cpack + b * 256;
  for (int k = 0; k < 80; k++) cp[k] = f2b(c[k]);            // id
  for (int k = 80; k < 96; k++) cp[k] = 0;                   // pad
  for (int k = 0; k < 64; k++) cp[96 + k] = f2b(c[80 + k]);  // ex
  for (int k = 0; k < 80; k++) cp[160 + k] = f2b(c[144 + k]);// tex
  for (int k = 240; k < 256; k++) cp[k] = 0;                 // pad
  float ax = c[224], ay = c[225], az = c[226];
  float sx = sinf(ax), cx = cosf(ax);
  float sy = sinf(ay), cy = cosf(ay);
  float sz = sinf(az), cz = cosf(az);
  float* M = rot + b * 9;
  M[0] = cz * cy;  M[1] = cz * sy * sx - sz * cx;  M[2] = sz * sx + cz * sy * cx;
  M[3] = sz * cy;  M[4] = cz * cx + sz * sy * sx;  M[5] = sz * sy * cx - cz * sx;
  M[6] = -sy;      M[7] = cy * sx;                 M[8] = cy * cx;
  float* g = G + b * 27;
  for (int cc = 0; cc < 9; cc++)
    for (int d = 0; d < 3; d++)
      g[cc * 3 + d] = c[227 + d * 9 + cc] + (cc == 0 ? 0.8f : 0.0f);
  float* t = tr + b * 3;
  t[0] = c[254]; t[1] = c[255]; t[2] = c[256];
}

// K2: MFMA GEMM; epilogue writes BATCH-MINOR transposed shpT/texT via per-wave LDS
// transpose (wave-private 1.5 KB window -> no cross-wave sync needed). Same write bytes,
// still fully coalesced (512 B f32 runs / 256 B u16 runs per window).
__global__ __launch_bounds__(256) void k_gemm(const float* __restrict__ idB, const float* __restrict__ exB,
                                              const float* __restrict__ txB, const float* __restrict__ ms,
                                              const float* __restrict__ mt, const u16* __restrict__ cpack,
                                              const float* __restrict__ meanc,
                                              float* __restrict__ shp, u16* __restrict__ texo) {
  __shared__ f2  sT[4][128];      // per-wave 2 windows x 128 f32
  __shared__ u32 tT[4][128];      // per-wave 2 windows x 128 u16
  int wave = threadIdx.x >> 6, lane = threadIdx.x & 63;
  int jt = blockIdx.x * 4 + wave;
  int col = lane & 15, quad = lane >> 4;
  int j = jt * 16 + col;
  bool jv = (j < NV3);
  int jc = jv ? j : (NV3 - 1);                 // clamped: loads always in-bounds
  bfrag z8 = {0, 0, 0, 0, 0, 0, 0, 0};
  bfrag bid[3], bex[2], btx[3];
  const float* rowI = idB + (size_t)jc * 80;
  const float* rowT = txB + (size_t)jc * 80;
  const float* rowE = exB + (size_t)jc * 64;
#pragma unroll
  for (int f = 0; f < 3; f++) {
    int k = f * 32 + quad * 8;
    bool ok = (k < 80);
    int ks = ok ? k : 0;
    bfrag vi = cvt8nt(rowI + ks);
    bfrag vt = cvt8nt(rowT + ks);
    bid[f] = ok ? vi : z8;
    btx[f] = ok ? vt : z8;
  }
#pragma unroll
  for (int f = 0; f < 2; f++) {
    int k = f * 32 + quad * 8;
    bex[f] = cvt8nt(rowE + k);
  }
  float msj = ms[jc];
  float mtj = mt[jc];
  float mc = meanc[jc % 3];

  float* sw = (float*)&sT[wave][0];
  u32* tw = &tT[wave][0];
  int s0 = quad >> 1;                          // which 8-batch window of this 16-batch tile
  int rbase = (quad & 1) << 2;                 // bi base = (quad&1)*4
  int sbase = s0 * 128 + col * 8 + rbase;

  for (int bt = 0; bt < 8; bt++) {
    const u16* cp = cpack + (size_t)(bt * 16 + col) * 256;
    ffrag accS = {0.f, 0.f, 0.f, 0.f};
    ffrag accT = {0.f, 0.f, 0.f, 0.f};
#pragma unroll
    for (int f = 0; f < 3; f++) {
      bfrag a = *(const bfrag*)(cp + f * 32 + quad * 8);
      accS = __builtin_amdgcn_mfma_f32_16x16x32_bf16(a, bid[f], accS, 0, 0, 0);
    }
#pragma unroll
    for (int f = 0; f < 2; f++) {
      bfrag a = *(const bfrag*)(cp + 96 + f * 32 + quad * 8);
      accS = __builtin_amdgcn_mfma_f32_16x16x32_bf16(a, bex[f], accS, 0, 0, 0);
    }
#pragma unroll
    for (int f = 0; f < 3; f++) {
      bfrag a = *(const bfrag*)(cp + 160 + f * 32 + quad * 8);
      accT = __builtin_amdgcn_mfma_f32_16x16x32_bf16(a, btx[f], accT, 0, 0, 0);
    }
    // stage transposed: slot index = window*128 + (j-j0)*8 + (b&7)
#pragma unroll
    for (int rr = 0; rr < 2; rr++) {
      f2 v2;
      v2.x = accS[2 * rr] + msj - mc;
      v2.y = accS[2 * rr + 1] + msj - mc;
      *(f2*)&sw[sbase + 2 * rr] = v2;
      tw[(sbase >> 1) + rr] = (u32)f2b(accT[2 * rr] + mtj) |
                              ((u32)f2b(accT[2 * rr + 1] + mtj) << 16);
    }
    // wave-private readback + coalesced store (compiler inserts lgkmcnt for LDS RAW)
#pragma unroll
    for (int s2 = 0; s2 < 2; s2++) {
      int o = lane << 1;                       // float offset within window, even
      int j2 = jt * 16 + (o >> 3);
      if (j2 < NV3) {
        size_t sb = (size_t)(bt * 2 + s2) * (size_t)(NV3 * 8);
        f2 vv = sT[wave][s2 * 64 + lane];
        __builtin_nontemporal_store(vv, (f2*)(shp + sb + (size_t)(jt * 128 + o)));
        u32 tv = tT[wave][s2 * 64 + lane];
        __builtin_nontemporal_store(tv, (u32*)(texo + sb + (size_t)(jt * 128 + o)));
      }
    }
  }
}

// K3: face normals, batch-minor. Wave = 8 faces x 8 batches: each vertex-component gather is
// 8 lanes x 32 B contiguous (~8 lines/instr instead of 64). Per-XCD shpT slab = 3.43 MB
// (L2-resident via bt8&7==xcd affinity). fn written as coalesced xy (f16x2) + z (f16) planes.
#define FN_CH2 2213   // ceil(NFACE/32)
__global__ __launch_bounds__(256) void k_fn(const float* __restrict__ shpT, const int* __restrict__ tri,
                                            u32* __restrict__ fxy, u16* __restrict__ fz) {
  int g = blockIdx.x;
  int xcd = g & 7, sgi = g >> 3;
  int btg = sgi / FN_CH2, chunk = sgi - btg * FN_CH2;
  int bt8 = btg * 8 + xcd;
  int t = threadIdx.x;
  int bi = t & 7, foff = t >> 3;
  int f = chunk * 32 + foff;
  if (f >= NFACE) return;
  int i0 = __builtin_nontemporal_load(tri + f * 3 + 0) - 1;
  int i1 = __builtin_nontemporal_load(tri + f * 3 + 1) - 1;
  int i2 = __builtin_nontemporal_load(tri + f * 3 + 2) - 1;
  const float* sl = shpT + (size_t)bt8 * (size_t)(NV3 * 8);
  int a0 = i0 * 24 + bi, a1 = i1 * 24 + bi, a2 = i2 * 24 + bi;
  float x1 = sl[a0], y1 = sl[a0 + 8], z1 = sl[a0 + 16];
  float x2 = sl[a1], y2 = sl[a1 + 8], z2 = sl[a1 + 16];
  float x3 = sl[a2], y3 = sl[a2 + 8], z3 = sl[a2 + 16];
  float e1x = x1 - x2, e1y = y1 - y2, e1z = z1 - z2;
  float e2x = x2 - x3, e2y = y2 - y3, e2z = z2 - z3;
  float cx = e1y * e2z - e1z * e2y;
  float cy = e1z * e2x - e1x * e2z;
  float cz = e1x * e2y - e1y * e2x;
  size_t o = (size_t)bt8 * (size_t)(NFACE * 8) + (size_t)f * 8 + bi;
  u32 xy = (u32)h2b(cx) | ((u32)h2b(cy) << 16);
  __builtin_nontemporal_store(xy, fxy + o);
  __builtin_nontemporal_store(h2b(cz), fz + o);
}

// K4: batch-minor vn gather (8 lanes/line, fn planes 2.26+1.13 MB L2-hot; streams are nt),
// rotate + SH lighting, outputs transposed back to [b][v][3] through a 6.4 KB LDS tile
// so out writes stay coalesced 384 B runs.
#define FI_CH2 1116   // ceil(NVERT/32)
__global__ __launch_bounds__(256) void k_final(const float* __restrict__ shpT, const u16* __restrict__ texT,
                                               const u32* __restrict__ fxy, const u16* __restrict__ fz,
                                               const int* __restrict__ pbuf,
                                               const float* __restrict__ rot, const float* __restrict__ G,
                                               const float* __restrict__ tr, float* __restrict__ out) {
  __shared__ float scol[8][100];   // [bi][voff*3+c], pad 96->100 to break bank aliasing
  __shared__ float sst[8][100];
  int g = blockIdx.x;
  int xcd = g & 7, sgi = g >> 3;
  int btg = sgi / FI_CH2, chunk = sgi - btg * FI_CH2;
  int bt8 = btg * 8 + xcd;
  int t = threadIdx.x;
  int bi = t & 7, voff = t >> 3;
  int v0 = chunk * 32;
  int v = v0 + voff;
  int vc = v < NVERT ? v : NVERT - 1;
  bool valid = v < NVERT;
  int b = bt8 * 8 + bi;
  i4 p0 = *(const i4*)(pbuf + (size_t)vc * 8);
  i4 p1 = *(const i4*)(pbuf + (size_t)vc * 8 + 4);
  int idx[8] = {p0.x, p0.y, p0.z, p0.w, p1.x, p1.y, p1.z, p1.w};
  const u32* fx = fxy + (size_t)bt8 * (size_t)(NFACE * 8);
  const u16* fzb = fz + (size_t)bt8 * (size_t)(NFACE * 8);
  float vx = 0.f, vy = 0.f, vz = 0.f;
#pragma unroll
  for (int i = 0; i < 8; i++) {
    int id = idx[i] - 1;               // in [0, NFACE]; NFACE == zero contribution
    if (id < NFACE) {
      u32 q = fx[(size_t)id * 8 + bi];
      u16 qz = fzb[(size_t)id * 8 + bi];
      vx += hb2f((u16)q); vy += hb2f((u16)(q >> 16)); vz += hb2f(qz);
    }
  }
  float n2 = vx * vx + vy * vy + vz * vz;
  float inv = rsqrtf(fmaxf(n2, 1e-30f));
  vx *= inv; vy *= inv; vz *= inv;
  const float* M = rot + b * 9;
  float nx = vx * M[0] + vy * M[1] + vz * M[2];
  float ny = vx * M[3] + vy * M[4] + vz * M[5];
  float nz = vx * M[6] + vy * M[7] + vz * M[8];
  const float* sl = shpT + (size_t)bt8 * (size_t)(NV3 * 8) + (size_t)vc * 24 + bi;
  float sx = __builtin_nontemporal_load(sl);
  float sy = __builtin_nontemporal_load(sl + 8);
  float sz = __builtin_nontemporal_load(sl + 16);
  const float* T = tr + b * 3;
  float ox = sx * M[0] + sy * M[1] + sz * M[2] + T[0];
  float oy = sx * M[3] + sy * M[4] + sz * M[5] + T[1];
  float oz = sx * M[6] + sy * M[7] + sz * M[8] + T[2];
  // SH lighting
  const float kc1 = 1.7724539f;             // a1*c1 = sqrt(pi)
  const float kc2 = 2.4270324f;             // a2*c2
  const float kd0 = 0.28867513f;            // 0.5/sqrt(3)
  float Y[9];
  Y[0] = 0.8862269f;                        // a0*c0
  Y[1] = -kc1 * ny;
  Y[2] = kc1 * nz;
  Y[3] = -kc1 * nx;
  Y[4] = kc2 * nx * ny;
  Y[5] = -kc2 * ny * nz;
  Y[6] = kc2 * kd0 * (3.f * nz * nz - 1.f);
  Y[7] = -kc2 * nx * nz;
  Y[8] = kc2 * 0.5f * (nx * nx - ny * ny);
  const float* gg = G + b * 27;
  const u16* tp = texT + (size_t)bt8 * (size_t)(NV3 * 8) + (size_t)vc * 24 + bi;
  if (valid) {
#pragma unroll
    for (int d = 0; d < 3; d++) {
      float L = 0.f;
#pragma unroll
      for (int cc = 0; cc < 9; cc++) L += Y[cc] * gg[cc * 3 + d];
      float tx = b2f(__builtin_nontemporal_load(tp + d * 8));
      scol[bi][voff * 3 + d] = tx * L;
    }
    sst[bi][voff * 3 + 0] = ox;
    sst[bi][voff * 3 + 1] = oy;
    sst[bi][voff * 3 + 2] = oz;
  }
  __syncthreads();
  int nvv = NVERT - v0;
  int lim = (nvv < 32 ? nvv : 32) * 3;
  size_t base = (size_t)(bt8 * 8) * NV3 + (size_t)v0 * 3;
#pragma unroll
  for (int it = 0; it < 3; it++) {
    int l = it * 256 + t;                  // 0..767
    int b2 = l / 96, e = l - b2 * 96;
    if (e < lim) {
      size_t o = base + (size_t)b2 * NV3 + e;
      __builtin_nontemporal_store(scol[b2][e], out + o);
      __builtin_nontemporal_store(sst[b2][e], out + ST_BASE + o);
    }
  }
}

// K5: landmarks — recompute shape_t at 68 kp verts from shpT, project (f32 out).
__global__ __launch_bounds__(128) void k_lms(const float* __restrict__ shpT, const int* __restrict__ kp,
                                             const float* __restrict__ rot, const float* __restrict__ tr,
                                             float* __restrict__ out) {
  int t = threadIdx.x;
  int b = blockIdx.x;
  if (t >= 68) return;
  int v = kp[t];
  const float* sl = shpT + (size_t)(b >> 3) * (size_t)(NV3 * 8) + (size_t)v * 24 + (b & 7);
  float sx = sl[0], sy = sl[8], sz = sl[16];
  const float* M = rot + b * 9;
  const float* T = tr + b * 3;
  float ox = sx * M[0] + sy * M[1] + sz * M[2] + T[0];
  float oy = sx * M[3] + sy * M[4] + sz * M[5] + T[1];
  float oz = sx * M[6] + sy * M[7] + sz * M[8] + T[2];
  float w = 10.f - oz;                      // pts@[1,1,-1] + [0,0,10]
  float invw = 1.0f / w;
  float lx = 1015.f * ox * invw + 128.f;    // FOCAL*x/w + half
  float ly = 1015.f * oy * invw + 128.f;
  size_t o = LMS_BASE + ((size_t)b * 68 + t) * 2;
  out[o + 0] = lx;
  out[o + 1] = 256.f - ly;                  // IMG - y
}

extern "C" void kernel_launch(void* const* d_in, const int* in_sizes, int n_in,
                              void* d_out, int out_size, void* d_ws, size_t ws_size,
                              hipStream_t stream) {
  const float* coeff     = (const float*)d_in[0];
  const float* meanshape = (const float*)d_in[1];
  const float* idB       = (const float*)d_in[2];
  const float* exB       = (const float*)d_in[3];
  const float* meantex   = (const float*)d_in[4];
  const float* txB       = (const float*)d_in[5];
  const int* tri         = (const int*)d_in[6];
  const int* pbuf        = (const int*)d_in[7];
  const int* kp          = (const int*)d_in[8];
  float* out = (float*)d_out;
  char* ws = (char*)d_ws;
  float* shpT = (float*)(ws + SHAPE_OFF);
  u16* texT   = (u16*)(ws + TEX_OFF);
  u32* fxy    = (u32*)(ws + FXY_OFF);
  u16* fzp    = (u16*)(ws + FZ_OFF);
  u16* cpack  = (u16*)(ws + CPACK_OFF);
  float* rot  = (float*)(ws + ROT_OFF);
  float* G    = (float*)(ws + G_OFF);
  float* tr   = (float*)(ws + TRANS_OFF);
  float* mean = (float*)(ws + MEAN_OFF);
  float* part = (float*)(ws + PART_OFF);

  k_mean<<<64, 256, 0, stream>>>(meanshape, part);
  k_params<<<1, 128, 0, stream>>>(coeff, cpack, rot, G, tr, part, mean);
  k_gemm<<<1674, 256, 0, stream>>>(idB, exB, txB, meanshape, meantex, cpack, mean, shpT, texT);
  k_fn<<<8 * 2 * FN_CH2, 256, 0, stream>>>(shpT, tri, fxy, fzp);
  k_final<<<8 * 2 * FI_CH2, 256, 0, stream>>>(shpT, texT, fxy, fzp, pbuf, rot, G, tr, out);
  k_lms<<<128, 128, 0, stream>>>(shpT, kp, rot, tr, out);
}

// Round 3
// 441.634 us; speedup vs baseline: 1.5714x; 1.0171x over previous
//
#include <hip/hip_runtime.h>

typedef unsigned short u16;
typedef unsigned int u32;
typedef __attribute__((ext_vector_type(8))) short bfrag;     // 8 bf16 (4 VGPRs) MFMA A/B
typedef __attribute__((ext_vector_type(4))) float ffrag;     // 4 f32 MFMA C/D
typedef __attribute__((ext_vector_type(4))) float f4;
typedef __attribute__((ext_vector_type(2))) float f2;        // clang vector: ok for nontemporal builtins
typedef __attribute__((ext_vector_type(4))) int i4;
typedef __attribute__((ext_vector_type(4))) _Float16 h4;     // fn record: xyz + pad, 8 B

#define NVERT 35709
#define NFACE 70789
#define NV3   107127
#define NB    128

// ---- workspace byte layout ----
// Batch-minor transposed internal layouts: bt8 = b>>3 (16 slabs), bi = b&7 innermost.
#define SHAPE_OFF 0ull            // f32 shpT[bt8][j][bi]  (54,849,024 B)  j = v*3+c
#define TEX_OFF   54849024ull     // u16 bf16 texT[bt8][j][bi] (27,424,512 B)
#define FQ_OFF    82273536ull     // h4 fn f16x4 [bt8][f][bi] (72,487,936 B) -> 64 B/line per 8-bi group
#define CPACK_OFF 154761472ull    // u16 bf16, NB*256 padded coeffs [id80|0*16|ex64|tex80|0*16]
#define ROT_OFF   154827008ull    // f32, NB*9  (M[d][c], M = Rz@Ry@Rx)
#define G_OFF     154831616ull    // f32, NB*27 (G[c][d] = gamma[d*9+c] + 0.8*(c==0))
#define TRANS_OFF 154845440ull    // f32, NB*3
#define MEAN_OFF  154846976ull    // f32, 3
#define PART_OFF  154847040ull    // f32, 64*3 partial sums for mean

// ---- output element offsets (f32 out) ----
#define LMS_BASE  13712256ull     // after face_color (B*NV*3)
#define ST_BASE   13729664ull     // after lms (B*68*2)

__device__ __forceinline__ float b2f(u16 s) {
  union { unsigned u; float f; } v; v.u = ((unsigned)s) << 16; return v.f;
}
__device__ __forceinline__ u16 f2b(float x) {  // f32 -> bf16 RNE
  union { float f; unsigned u; } v; v.f = x;
  unsigned r = v.u + 0x7FFFu + ((v.u >> 16) & 1u);
  return (u16)(r >> 16);
}
__device__ __forceinline__ bfrag cvt8nt(const float* p) {  // 8 f32 (nt) -> 8 bf16
  f4 a = __builtin_nontemporal_load((const f4*)p);
  f4 b = __builtin_nontemporal_load((const f4*)(p + 4));
  bfrag r;
  r[0] = (short)f2b(a.x); r[1] = (short)f2b(a.y); r[2] = (short)f2b(a.z); r[3] = (short)f2b(a.w);
  r[4] = (short)f2b(b.x); r[5] = (short)f2b(b.y); r[6] = (short)f2b(b.z); r[7] = (short)f2b(b.w);
  return r;
}

// K0: partial sums of meanshape over vertices (64 blocks x 3 comps)
__global__ __launch_bounds__(256) void k_mean(const float* __restrict__ ms, float* __restrict__ part) {
  __shared__ float s[3];
  if (threadIdx.x < 3) s[threadIdx.x] = 0.f;
  __syncthreads();
  float a0 = 0.f, a1 = 0.f, a2 = 0.f;
  for (int v = blockIdx.x * 256 + threadIdx.x; v < NVERT; v += 64 * 256) {
    a0 += ms[v * 3 + 0];
    a1 += ms[v * 3 + 1];
    a2 += ms[v * 3 + 2];
  }
  atomicAdd(&s[0], a0); atomicAdd(&s[1], a1); atomicAdd(&s[2], a2);
  __syncthreads();
  if (threadIdx.x < 3) part[blockIdx.x * 3 + threadIdx.x] = s[threadIdx.x];
}

// K1: finalize mean; per-batch params
__global__ __launch_bounds__(128) void k_params(const float* __restrict__ coeff, u16* __restrict__ cpack,
                                                float* __restrict__ rot, float* __restrict__ G,
                                                float* __restrict__ tr, const float* __restrict__ part,
                                                float* __restrict__ mean) {
  int b = threadIdx.x;
  if (b < 3) {
    float s = 0.f;
    for (int i = 0; i < 64; i++) s += part[i * 3 + b];
    mean[b] = s * (1.0f / (float)NVERT);
  }
  const float* c = coeff + b * 257;
  u16* cp = cpack + b * 256;
  for (int k = 0; k < 80; k++) cp[k] = f2b(c[k]);            // id
  for (int k = 80; k < 96; k++) cp[k] = 0;                   // pad
  for (int k = 0; k < 64; k++) cp[96 + k] = f2b(c[80 + k]);  // ex
  for (int k = 0; k < 80; k++) cp[160 + k] = f2b(c[144 + k]);// tex
  for (int k = 240; k < 256; k++) cp[k] = 0;                 // pad
  float ax = c[224], ay = c[225], az = c[226];
  float sx = sinf(ax), cx = cosf(ax);
  float sy = sinf(ay), cy = cosf(ay);
  float sz = sinf(az), cz = cosf(az);
  float* M = rot + b * 9;
  M[0] = cz * cy;  M[1] = cz * sy * sx - sz * cx;  M[2] = sz * sx + cz * sy * cx;
  M[3] = sz * cy;  M[4] = cz * cx + sz * sy * sx;  M[5] = sz * sy * cx - cz * sx;
  M[6] = -sy;      M[7] = cy * sx;                 M[8] = cy * cx;
  float* g = G + b * 27;
  for (int cc = 0; cc < 9; cc++)
    for (int d = 0; d < 3; d++)
      g[cc * 3 + d] = c[227 + d * 9 + cc] + (cc == 0 ? 0.8f : 0.0f);
  float* t = tr + b * 3;
  t[0] = c[254]; t[1] = c[255]; t[2] = c[256];
}

// K2: MFMA GEMM; epilogue writes BATCH-MINOR transposed shpT/texT via per-wave LDS
// transpose (wave-private 1.5 KB window -> no cross-wave sync needed).
__global__ __launch_bounds__(256) void k_gemm(const float* __restrict__ idB, const float* __restrict__ exB,
                                              const float* __restrict__ txB, const float* __restrict__ ms,
                                              const float* __restrict__ mt, const u16* __restrict__ cpack,
                                              const float* __restrict__ meanc,
                                              float* __restrict__ shp, u16* __restrict__ texo) {
  __shared__ f2  sT[4][128];      // per-wave 2 windows x 128 f32
  __shared__ u32 tT[4][128];      // per-wave 2 windows x 128 u16
  int wave = threadIdx.x >> 6, lane = threadIdx.x & 63;
  int jt = blockIdx.x * 4 + wave;
  int col = lane & 15, quad = lane >> 4;
  int j = jt * 16 + col;
  bool jv = (j < NV3);
  int jc = jv ? j : (NV3 - 1);                 // clamped: loads always in-bounds
  bfrag z8 = {0, 0, 0, 0, 0, 0, 0, 0};
  bfrag bid[3], bex[2], btx[3];
  const float* rowI = idB + (size_t)jc * 80;
  const float* rowT = txB + (size_t)jc * 80;
  const float* rowE = exB + (size_t)jc * 64;
#pragma unroll
  for (int f = 0; f < 3; f++) {
    int k = f * 32 + quad * 8;
    bool ok = (k < 80);
    int ks = ok ? k : 0;
    bfrag vi = cvt8nt(rowI + ks);
    bfrag vt = cvt8nt(rowT + ks);
    bid[f] = ok ? vi : z8;
    btx[f] = ok ? vt : z8;
  }
#pragma unroll
  for (int f = 0; f < 2; f++) {
    int k = f * 32 + quad * 8;
    bex[f] = cvt8nt(rowE + k);
  }
  float msj = ms[jc];
  float mtj = mt[jc];
  float mc = meanc[jc % 3];

  float* sw = (float*)&sT[wave][0];
  u32* tw = &tT[wave][0];
  int s0 = quad >> 1;                          // which 8-batch window of this 16-batch tile
  int rbase = (quad & 1) << 2;                 // bi base = (quad&1)*4
  int sbase = s0 * 128 + col * 8 + rbase;

  for (int bt = 0; bt < 8; bt++) {
    const u16* cp = cpack + (size_t)(bt * 16 + col) * 256;
    ffrag accS = {0.f, 0.f, 0.f, 0.f};
    ffrag accT = {0.f, 0.f, 0.f, 0.f};
#pragma unroll
    for (int f = 0; f < 3; f++) {
      bfrag a = *(const bfrag*)(cp + f * 32 + quad * 8);
      accS = __builtin_amdgcn_mfma_f32_16x16x32_bf16(a, bid[f], accS, 0, 0, 0);
    }
#pragma unroll
    for (int f = 0; f < 2; f++) {
      bfrag a = *(const bfrag*)(cp + 96 + f * 32 + quad * 8);
      accS = __builtin_amdgcn_mfma_f32_16x16x32_bf16(a, bex[f], accS, 0, 0, 0);
    }
#pragma unroll
    for (int f = 0; f < 3; f++) {
      bfrag a = *(const bfrag*)(cp + 160 + f * 32 + quad * 8);
      accT = __builtin_amdgcn_mfma_f32_16x16x32_bf16(a, btx[f], accT, 0, 0, 0);
    }
    // stage transposed: slot index = window*128 + (j-j0)*8 + (b&7)
#pragma unroll
    for (int rr = 0; rr < 2; rr++) {
      f2 v2;
      v2.x = accS[2 * rr] + msj - mc;
      v2.y = accS[2 * rr + 1] + msj - mc;
      *(f2*)&sw[sbase + 2 * rr] = v2;
      tw[(sbase >> 1) + rr] = (u32)f2b(accT[2 * rr] + mtj) |
                              ((u32)f2b(accT[2 * rr + 1] + mtj) << 16);
    }
    // wave-private readback + coalesced store (compiler inserts lgkmcnt for LDS RAW)
#pragma unroll
    for (int s2 = 0; s2 < 2; s2++) {
      int o = lane << 1;                       // float offset within window, even
      int j2 = jt * 16 + (o >> 3);
      if (j2 < NV3) {
        size_t sb = (size_t)(bt * 2 + s2) * (size_t)(NV3 * 8);
        f2 vv = sT[wave][s2 * 64 + lane];
        __builtin_nontemporal_store(vv, (f2*)(shp + sb + (size_t)(jt * 128 + o)));
        u32 tv = tT[wave][s2 * 64 + lane];
        __builtin_nontemporal_store(tv, (u32*)(texo + sb + (size_t)(jt * 128 + o)));
      }
    }
  }
}

// K3: face normals, batch-minor, FUSED f16x4 record: one 8 B nt store; the consumer-side
// gather becomes one dwordx2 per face (8-bi group = exactly one aligned 64 B line).
#define FN_CH2 2213   // ceil(NFACE/32)
__global__ __launch_bounds__(256) void k_fn(const float* __restrict__ shpT, const int* __restrict__ tri,
                                            h4* __restrict__ fq) {
  int g = blockIdx.x;
  int xcd = g & 7, sgi = g >> 3;
  int btg = sgi / FN_CH2, chunk = sgi - btg * FN_CH2;
  int bt8 = btg * 8 + xcd;
  int t = threadIdx.x;
  int bi = t & 7, foff = t >> 3;
  int f = chunk * 32 + foff;
  if (f >= NFACE) return;
  int i0 = __builtin_nontemporal_load(tri + f * 3 + 0) - 1;
  int i1 = __builtin_nontemporal_load(tri + f * 3 + 1) - 1;
  int i2 = __builtin_nontemporal_load(tri + f * 3 + 2) - 1;
  const float* sl = shpT + (size_t)bt8 * (size_t)(NV3 * 8);
  int a0 = i0 * 24 + bi, a1 = i1 * 24 + bi, a2 = i2 * 24 + bi;
  float x1 = sl[a0], y1 = sl[a0 + 8], z1 = sl[a0 + 16];
  float x2 = sl[a1], y2 = sl[a1 + 8], z2 = sl[a1 + 16];
  float x3 = sl[a2], y3 = sl[a2 + 8], z3 = sl[a2 + 16];
  float e1x = x1 - x2, e1y = y1 - y2, e1z = z1 - z2;
  float e2x = x2 - x3, e2y = y2 - y3, e2z = z2 - z3;
  h4 st;
  st.x = (_Float16)(e1y * e2z - e1z * e2y);
  st.y = (_Float16)(e1z * e2x - e1x * e2z);
  st.z = (_Float16)(e1x * e2y - e1y * e2x);
  st.w = (_Float16)0.f;
  __builtin_nontemporal_store(st, fq + (size_t)bt8 * (size_t)(NFACE * 8) + (size_t)f * 8 + bi);
}

// K4: batch-minor vn gather — now 8 dwordx2 gathers (1 line per 8-bi group per face),
// rotate + SH lighting, outputs transposed back to [b][v][3] through a 6.4 KB LDS tile.
#define FI_CH2 1116   // ceil(NVERT/32)
__global__ __launch_bounds__(256) void k_final(const float* __restrict__ shpT, const u16* __restrict__ texT,
                                               const h4* __restrict__ fq, const int* __restrict__ pbuf,
                                               const float* __restrict__ rot, const float* __restrict__ G,
                                               const float* __restrict__ tr, float* __restrict__ out) {
  __shared__ float scol[8][100];   // [bi][voff*3+c], pad 96->100 to break bank aliasing
  __shared__ float sst[8][100];
  int g = blockIdx.x;
  int xcd = g & 7, sgi = g >> 3;
  int btg = sgi / FI_CH2, chunk = sgi - btg * FI_CH2;
  int bt8 = btg * 8 + xcd;
  int t = threadIdx.x;
  int bi = t & 7, voff = t >> 3;
  int v0 = chunk * 32;
  int v = v0 + voff;
  int vc = v < NVERT ? v : NVERT - 1;
  bool valid = v < NVERT;
  int b = bt8 * 8 + bi;
  i4 p0 = *(const i4*)(pbuf + (size_t)vc * 8);
  i4 p1 = *(const i4*)(pbuf + (size_t)vc * 8 + 4);
  int idx[8] = {p0.x, p0.y, p0.z, p0.w, p1.x, p1.y, p1.z, p1.w};
  const h4* fb = fq + (size_t)bt8 * (size_t)(NFACE * 8);
  float vx = 0.f, vy = 0.f, vz = 0.f;
#pragma unroll
  for (int i = 0; i < 8; i++) {
    int id = idx[i] - 1;               // in [0, NFACE]; NFACE == zero contribution
    if (id < NFACE) {
      h4 q = fb[(size_t)id * 8 + bi];
      vx += (float)q.x; vy += (float)q.y; vz += (float)q.z;
    }
  }
  float n2 = vx * vx + vy * vy + vz * vz;
  float inv = rsqrtf(fmaxf(n2, 1e-30f));
  vx *= inv; vy *= inv; vz *= inv;
  const float* M = rot + b * 9;
  float nx = vx * M[0] + vy * M[1] + vz * M[2];
  float ny = vx * M[3] + vy * M[4] + vz * M[5];
  float nz = vx * M[6] + vy * M[7] + vz * M[8];
  const float* sl = shpT + (size_t)bt8 * (size_t)(NV3 * 8) + (size_t)vc * 24 + bi;
  float sx = __builtin_nontemporal_load(sl);
  float sy = __builtin_nontemporal_load(sl + 8);
  float sz = __builtin_nontemporal_load(sl + 16);
  const float* T = tr + b * 3;
  float ox = sx * M[0] + sy * M[1] + sz * M[2] + T[0];
  float oy = sx * M[3] + sy * M[4] + sz * M[5] + T[1];
  float oz = sx * M[6] + sy * M[7] + sz * M[8] + T[2];
  // SH lighting
  const float kc1 = 1.7724539f;             // a1*c1 = sqrt(pi)
  const float kc2 = 2.4270324f;             // a2*c2
  const float kd0 = 0.28867513f;            // 0.5/sqrt(3)
  float Y[9];
  Y[0] = 0.8862269f;                        // a0*c0
  Y[1] = -kc1 * ny;
  Y[2] = kc1 * nz;
  Y[3] = -kc1 * nx;
  Y[4] = kc2 * nx * ny;
  Y[5] = -kc2 * ny * nz;
  Y[6] = kc2 * kd0 * (3.f * nz * nz - 1.f);
  Y[7] = -kc2 * nx * nz;
  Y[8] = kc2 * 0.5f * (nx * nx - ny * ny);
  const float* gg = G + b * 27;
  const u16* tp = texT + (size_t)bt8 * (size_t)(NV3 * 8) + (size_t)vc * 24 + bi;
  if (valid) {
#pragma unroll
    for (int d = 0; d < 3; d++) {
      float L = 0.f;
#pragma unroll
      for (int cc = 0; cc < 9; cc++) L += Y[cc] * gg[cc * 3 + d];
      float tx = b2f(__builtin_nontemporal_load(tp + d * 8));
      scol[bi][voff * 3 + d] = tx * L;
    }
    sst[bi][voff * 3 + 0] = ox;
    sst[bi][voff * 3 + 1] = oy;
    sst[bi][voff * 3 + 2] = oz;
  }
  __syncthreads();
  int nvv = NVERT - v0;
  int lim = (nvv < 32 ? nvv : 32) * 3;
  size_t base = (size_t)(bt8 * 8) * NV3 + (size_t)v0 * 3;
#pragma unroll
  for (int it = 0; it < 3; it++) {
    int l = it * 256 + t;                  // 0..767
    int b2 = l / 96, e = l - b2 * 96;
    if (e < lim) {
      size_t o = base + (size_t)b2 * NV3 + e;
      __builtin_nontemporal_store(scol[b2][e], out + o);
      __builtin_nontemporal_store(sst[b2][e], out + ST_BASE + o);
    }
  }
}

// K5: landmarks — recompute shape_t at 68 kp verts from shpT, project (f32 out).
__global__ __launch_bounds__(128) void k_lms(const float* __restrict__ shpT, const int* __restrict__ kp,
                                             const float* __restrict__ rot, const float* __restrict__ tr,
                                             float* __restrict__ out) {
  int t = threadIdx.x;
  int b = blockIdx.x;
  if (t >= 68) return;
  int v = kp[t];
  const float* sl = shpT + (size_t)(b >> 3) * (size_t)(NV3 * 8) + (size_t)v * 24 + (b & 7);
  float sx = sl[0], sy = sl[8], sz = sl[16];
  const float* M = rot + b * 9;
  const float* T = tr + b * 3;
  float ox = sx * M[0] + sy * M[1] + sz * M[2] + T[0];
  float oy = sx * M[3] + sy * M[4] + sz * M[5] + T[1];
  float oz = sx * M[6] + sy * M[7] + sz * M[8] + T[2];
  float w = 10.f - oz;                      // pts@[1,1,-1] + [0,0,10]
  float invw = 1.0f / w;
  float lx = 1015.f * ox * invw + 128.f;    // FOCAL*x/w + half
  float ly = 1015.f * oy * invw + 128.f;
  size_t o = LMS_BASE + ((size_t)b * 68 + t) * 2;
  out[o + 0] = lx;
  out[o + 1] = 256.f - ly;                  // IMG - y
}

extern "C" void kernel_launch(void* const* d_in, const int* in_sizes, int n_in,
                              void* d_out, int out_size, void* d_ws, size_t ws_size,
                              hipStream_t stream) {
  const float* coeff     = (const float*)d_in[0];
  const float* meanshape = (const float*)d_in[1];
  const float* idB       = (const float*)d_in[2];
  const float* exB       = (const float*)d_in[3];
  const float* meantex   = (const float*)d_in[4];
  const float* txB       = (const float*)d_in[5];
  const int* tri         = (const int*)d_in[6];
  const int* pbuf        = (const int*)d_in[7];
  const int* kp          = (const int*)d_in[8];
  float* out = (float*)d_out;
  char* ws = (char*)d_ws;
  float* shpT = (float*)(ws + SHAPE_OFF);
  u16* texT   = (u16*)(ws + TEX_OFF);
  h4* fq      = (h4*)(ws + FQ_OFF);
  u16* cpack  = (u16*)(ws + CPACK_OFF);
  float* rot  = (float*)(ws + ROT_OFF);
  float* G    = (float*)(ws + G_OFF);
  float* tr   = (float*)(ws + TRANS_OFF);
  float* mean = (float*)(ws + MEAN_OFF);
  float* part = (float*)(ws + PART_OFF);

  k_mean<<<64, 256, 0, stream>>>(meanshape, part);
  k_params<<<1, 128, 0, stream>>>(coeff, cpack, rot, G, tr, part, mean);
  k_gemm<<<1674, 256, 0, stream>>>(idB, exB, txB, meanshape, meantex, cpack, mean, shpT, texT);
  k_fn<<<8 * 2 * FN_CH2, 256, 0, stream>>>(shpT, tri, fq);
  k_final<<<8 * 2 * FI_CH2, 256, 0, stream>>>(shpT, texT, fq, pbuf, rot, G, tr, out);
  k_lms<<<128, 128, 0, stream>>>(shpT, kp, rot, tr, out);
}

// Round 4
// 420.136 us; speedup vs baseline: 1.6518x; 1.0512x over previous
//
#include <hip/hip_runtime.h>

typedef unsigned short u16;
typedef unsigned int u32;
typedef __attribute__((ext_vector_type(8))) short bfrag;     // 8 bf16 (4 VGPRs) MFMA A/B
typedef __attribute__((ext_vector_type(4))) float ffrag;     // 4 f32 MFMA C/D
typedef __attribute__((ext_vector_type(4))) float f4;
typedef __attribute__((ext_vector_type(2))) float f2;        // clang vector: ok for nontemporal builtins
typedef __attribute__((ext_vector_type(4))) int i4;
typedef __attribute__((ext_vector_type(4))) _Float16 h4;     // fn record: xyz + pad, 8 B

#define NVERT 35709
#define NFACE 70789
#define NV3   107127
#define NB    128

// ---- workspace byte layout ----
// Batch-minor transposed internal layouts: bt8 = b>>3 (16 slabs), bi = b&7 innermost.
#define SHAPE_OFF 0ull            // f32 shpT[bt8][j][bi]  (54,849,024 B)  j = v*3+c
#define TEX_OFF   54849024ull     // u16 bf16 texT[bt8][j][bi] (27,424,512 B)
#define FQ_OFF    82273536ull     // h4 fn f16x4 [bt8][f][bi] (72,487,936 B)
#define CPACK_OFF 154761472ull    // u16 bf16, NB*256 padded coeffs [id80|0*16|ex64|tex80|0*16]
#define MPAD_OFF  154827008ull    // f32 [128][12]: M[0..8], T[9..11] (48 B rows, 16 B aligned)
#define GG_OFF    154833152ull    // f32 [128][27]: G[cc*3+d]
#define MEAN_OFF  154846976ull    // f32, 3 (+1 pad)
#define PART_OFF  154846992ull    // f32, 64*3 partial sums for mean (end 154847760)

// ---- output element offsets (f32 out) ----
#define LMS_BASE  13712256ull     // after face_color (B*NV*3)
#define ST_BASE   13729664ull     // after lms (B*68*2)

__device__ __forceinline__ float b2f(u16 s) {
  union { unsigned u; float f; } v; v.u = ((unsigned)s) << 16; return v.f;
}
__device__ __forceinline__ u16 f2b(float x) {  // f32 -> bf16 RNE
  union { float f; unsigned u; } v; v.f = x;
  unsigned r = v.u + 0x7FFFu + ((v.u >> 16) & 1u);
  return (u16)(r >> 16);
}
__device__ __forceinline__ f4 ld4u(const float* p) {  // 16 B load, 4 B aligned
  f4 r; __builtin_memcpy(&r, p, 16); return r;
}
__device__ __forceinline__ bfrag cvt8nt(const float* p) {  // 8 f32 (nt) -> 8 bf16
  f4 a = __builtin_nontemporal_load((const f4*)p);
  f4 b = __builtin_nontemporal_load((const f4*)(p + 4));
  bfrag r;
  r[0] = (short)f2b(a.x); r[1] = (short)f2b(a.y); r[2] = (short)f2b(a.z); r[3] = (short)f2b(a.w);
  r[4] = (short)f2b(b.x); r[5] = (short)f2b(b.y); r[6] = (short)f2b(b.z); r[7] = (short)f2b(b.w);
  return r;
}

// K0: partial sums of meanshape over vertices (64 blocks x 3 comps)
__global__ __launch_bounds__(256) void k_mean(const float* __restrict__ ms, float* __restrict__ part) {
  __shared__ float s[3];
  if (threadIdx.x < 3) s[threadIdx.x] = 0.f;
  __syncthreads();
  float a0 = 0.f, a1 = 0.f, a2 = 0.f;
  for (int v = blockIdx.x * 256 + threadIdx.x; v < NVERT; v += 64 * 256) {
    a0 += ms[v * 3 + 0];
    a1 += ms[v * 3 + 1];
    a2 += ms[v * 3 + 2];
  }
  atomicAdd(&s[0], a0); atomicAdd(&s[1], a1); atomicAdd(&s[2], a2);
  __syncthreads();
  if (threadIdx.x < 3) part[blockIdx.x * 3 + threadIdx.x] = s[threadIdx.x];
}

// K1: finalize mean; per-batch params: cpack bf16 coeffs, mpad[b][12] = M[9]+T[3], G[b][27]
__global__ __launch_bounds__(128) void k_params(const float* __restrict__ coeff, u16* __restrict__ cpack,
                                                float* __restrict__ mpad, float* __restrict__ G,
                                                const float* __restrict__ part, float* __restrict__ mean) {
  int b = threadIdx.x;
  if (b < 3) {
    float s = 0.f;
    for (int i = 0; i < 64; i++) s += part[i * 3 + b];
    mean[b] = s * (1.0f / (float)NVERT);
  }
  const float* c = coeff + b * 257;
  u16* cp = cpack + b * 256;
  for (int k = 0; k < 80; k++) cp[k] = f2b(c[k]);            // id
  for (int k = 80; k < 96; k++) cp[k] = 0;                   // pad
  for (int k = 0; k < 64; k++) cp[96 + k] = f2b(c[80 + k]);  // ex
  for (int k = 0; k < 80; k++) cp[160 + k] = f2b(c[144 + k]);// tex
  for (int k = 240; k < 256; k++) cp[k] = 0;                 // pad
  float ax = c[224], ay = c[225], az = c[226];
  float sx = sinf(ax), cx = cosf(ax);
  float sy = sinf(ay), cy = cosf(ay);
  float sz = sinf(az), cz = cosf(az);
  float* mp = mpad + b * 12;
  mp[0] = cz * cy;  mp[1] = cz * sy * sx - sz * cx;  mp[2] = sz * sx + cz * sy * cx;
  mp[3] = sz * cy;  mp[4] = cz * cx + sz * sy * sx;  mp[5] = sz * sy * cx - cz * sx;
  mp[6] = -sy;      mp[7] = cy * sx;                 mp[8] = cy * cx;
  mp[9] = c[254]; mp[10] = c[255]; mp[11] = c[256];
  float* g = G + b * 27;
  for (int cc = 0; cc < 9; cc++)
    for (int d = 0; d < 3; d++)
      g[cc * 3 + d] = c[227 + d * 9 + cc] + (cc == 0 ? 0.8f : 0.0f);
}

// K2a: shape GEMM. Wave owns 48 j = exactly 16 vertices (3 MFMA tiles), stages all 3 tiles
// in wave-private LDS, then (a) copies raw shape -> shpT (for k_fn/k_lms) and (b) rotates
// per-vertex and writes shape_t directly to out (removes k_final's 55 MB stream).
#define SBLK 558   // ceil(NV3 / 192)
__global__ __launch_bounds__(256) void k_gemmS(const float* __restrict__ idB, const float* __restrict__ exB,
                                               const float* __restrict__ ms, const u16* __restrict__ cpack,
                                               const float* __restrict__ meanc, const float* __restrict__ mpad,
                                               float* __restrict__ shp, float* __restrict__ out) {
  __shared__ float SW[4][2][384];   // [wave][window s][48 j * 8 bi]
  int wave = threadIdx.x >> 6, lane = threadIdx.x & 63;
  int col = lane & 15, quad = lane >> 4;
  int jb = (blockIdx.x * 4 + wave) * 48;
  bfrag z8 = {0, 0, 0, 0, 0, 0, 0, 0};
  bfrag bid[3][3], bex[3][2];
  float msj[3], mcv[3];
#pragma unroll
  for (int T = 0; T < 3; T++) {
    int j = jb + T * 16 + col;
    int jc = j < NV3 ? j : NV3 - 1;
    const float* rowI = idB + (size_t)jc * 80;
    const float* rowE = exB + (size_t)jc * 64;
#pragma unroll
    for (int f = 0; f < 3; f++) {
      int k = f * 32 + quad * 8;
      bool ok = (k < 80);
      int ks = ok ? k : 0;
      bfrag vi = cvt8nt(rowI + ks);
      bid[T][f] = ok ? vi : z8;
    }
#pragma unroll
    for (int f = 0; f < 2; f++) bex[T][f] = cvt8nt(rowE + f * 32 + quad * 8);
    msj[T] = ms[jc];
    mcv[T] = meanc[jc % 3];
  }
  float (*SWl)[384] = SW[wave];
  int s0 = quad >> 1;
  int rb = (quad & 1) << 2;
  int vb = jb / 3;
  int ilim = NV3 - jb; ilim = (ilim > 48 ? 48 : ilim) * 8;
  int vlim = NVERT - vb; vlim = vlim > 16 ? 16 : vlim;

  for (int bt = 0; bt < 8; bt++) {
    const u16* cp = cpack + (size_t)(bt * 16 + col) * 256;
#pragma unroll
    for (int T = 0; T < 3; T++) {
      ffrag acc = {0.f, 0.f, 0.f, 0.f};
#pragma unroll
      for (int f = 0; f < 3; f++) {
        bfrag a = *(const bfrag*)(cp + f * 32 + quad * 8);
        acc = __builtin_amdgcn_mfma_f32_16x16x32_bf16(a, bid[T][f], acc, 0, 0, 0);
      }
#pragma unroll
      for (int f = 0; f < 2; f++) {
        bfrag a = *(const bfrag*)(cp + 96 + f * 32 + quad * 8);
        acc = __builtin_amdgcn_mfma_f32_16x16x32_bf16(a, bex[T][f], acc, 0, 0, 0);
      }
#pragma unroll
      for (int rr = 0; rr < 2; rr++) {
        f2 v2;
        v2.x = acc[2 * rr] + msj[T] - mcv[T];
        v2.y = acc[2 * rr + 1] + msj[T] - mcv[T];
        *(f2*)&SWl[s0][(T * 16 + col) * 8 + rb + 2 * rr] = v2;
      }
    }
    // raw shpT copy (coalesced, wave-private LDS -> compiler handles lgkmcnt)
#pragma unroll
    for (int s = 0; s < 2; s++) {
      size_t sb = (size_t)(bt * 2 + s) * (size_t)(NV3 * 8) + (size_t)jb * 8;
#pragma unroll
      for (int it = 0; it < 3; it++) {
        int i = it * 128 + lane * 2;
        if (i < ilim) {
          f2 vv = *(f2*)&SWl[s][i];
          __builtin_nontemporal_store(vv, (f2*)(shp + sb + i));
        }
      }
    }
    // rotated shape_t -> out (16 verts x 8 bi per window; lane = bi-group*16 + vloc)
#pragma unroll
    for (int s = 0; s < 2; s++) {
#pragma unroll
      for (int kk = 0; kk < 2; kk++) {
        int bi = (lane >> 4) + (kk << 2);
        int vloc = lane & 15;
        int b = bt * 16 + s * 8 + bi;
        float x = SWl[s][vloc * 24 + bi];
        float y = SWl[s][vloc * 24 + 8 + bi];
        float z = SWl[s][vloc * 24 + 16 + bi];
        const float* mp = mpad + b * 12;
        f4 m0 = *(const f4*)mp;
        f4 m1 = *(const f4*)(mp + 4);
        f4 m2 = *(const f4*)(mp + 8);
        if (vloc < vlim) {
          float ox = x * m0.x + y * m0.y + z * m0.z + m2.y;
          float oy = x * m0.w + y * m1.x + z * m1.y + m2.z;
          float oz = x * m1.z + y * m1.w + z * m2.x + m2.w;
          size_t o = ST_BASE + (size_t)b * NV3 + (size_t)(vb + vloc) * 3;
          __builtin_nontemporal_store(ox, out + o);
          __builtin_nontemporal_store(oy, out + o + 1);
          __builtin_nontemporal_store(oz, out + o + 2);
        }
      }
    }
  }
}

// K2b: tex GEMM (old structure, tex only) -> texT batch-minor
__global__ __launch_bounds__(256) void k_gemmT(const float* __restrict__ txB, const float* __restrict__ mt,
                                               const u16* __restrict__ cpack, u16* __restrict__ texo) {
  __shared__ u32 tT[4][128];
  int wave = threadIdx.x >> 6, lane = threadIdx.x & 63;
  int jt = blockIdx.x * 4 + wave;
  int col = lane & 15, quad = lane >> 4;
  int j = jt * 16 + col;
  int jc = j < NV3 ? j : NV3 - 1;
  bfrag z8 = {0, 0, 0, 0, 0, 0, 0, 0};
  bfrag btx[3];
  const float* rowT = txB + (size_t)jc * 80;
#pragma unroll
  for (int f = 0; f < 3; f++) {
    int k = f * 32 + quad * 8;
    bool ok = (k < 80);
    int ks = ok ? k : 0;
    bfrag vt = cvt8nt(rowT + ks);
    btx[f] = ok ? vt : z8;
  }
  float mtj = mt[jc];
  u32* tw = &tT[wave][0];
  int slot = (quad >> 1) * 64 + col * 4 + (quad & 1) * 2;

  for (int bt = 0; bt < 8; bt++) {
    const u16* cp = cpack + (size_t)(bt * 16 + col) * 256;
    ffrag accT = {0.f, 0.f, 0.f, 0.f};
#pragma unroll
    for (int f = 0; f < 3; f++) {
      bfrag a = *(const bfrag*)(cp + 160 + f * 32 + quad * 8);
      accT = __builtin_amdgcn_mfma_f32_16x16x32_bf16(a, btx[f], accT, 0, 0, 0);
    }
#pragma unroll
    for (int rr = 0; rr < 2; rr++)
      tw[slot + rr] = (u32)f2b(accT[2 * rr] + mtj) | ((u32)f2b(accT[2 * rr + 1] + mtj) << 16);
#pragma unroll
    for (int s2 = 0; s2 < 2; s2++) {
      int o = lane << 1;
      int j2 = jt * 16 + (o >> 3);
      if (j2 < NV3) {
        size_t sb = (size_t)(bt * 2 + s2) * (size_t)(NV3 * 8);
        u32 tv = tT[wave][s2 * 64 + lane];
        __builtin_nontemporal_store(tv, (u32*)(texo + sb + (size_t)(jt * 128 + o)));
      }
    }
  }
}

// K3: face normals, batch-minor fused f16x4. tri loads CACHED (read 16x per launch);
// fq stores CACHED (slab is XCD-affine; k_final re-reads it from same XCD's L2).
#define FN_CH2 2213   // ceil(NFACE/32)
__global__ __launch_bounds__(256) void k_fn(const float* __restrict__ shpT, const int* __restrict__ tri,
                                            h4* __restrict__ fq) {
  int g = blockIdx.x;
  int xcd = g & 7, sgi = g >> 3;
  int btg = sgi / FN_CH2, chunk = sgi - btg * FN_CH2;
  int bt8 = btg * 8 + xcd;
  int t = threadIdx.x;
  int bi = t & 7, foff = t >> 3;
  int f = chunk * 32 + foff;
  if (f >= NFACE) return;
  int i0 = tri[f * 3 + 0] - 1;
  int i1 = tri[f * 3 + 1] - 1;
  int i2 = tri[f * 3 + 2] - 1;
  const float* sl = shpT + (size_t)bt8 * (size_t)(NV3 * 8);
  int a0 = i0 * 24 + bi, a1 = i1 * 24 + bi, a2 = i2 * 24 + bi;
  float x1 = sl[a0], y1 = sl[a0 + 8], z1 = sl[a0 + 16];
  float x2 = sl[a1], y2 = sl[a1 + 8], z2 = sl[a1 + 16];
  float x3 = sl[a2], y3 = sl[a2 + 8], z3 = sl[a2 + 16];
  float e1x = x1 - x2, e1y = y1 - y2, e1z = z1 - z2;
  float e2x = x2 - x3, e2y = y2 - y3, e2z = z2 - z3;
  h4 st;
  st.x = (_Float16)(e1y * e2z - e1z * e2y);
  st.y = (_Float16)(e1z * e2x - e1x * e2z);
  st.z = (_Float16)(e1x * e2y - e1y * e2x);
  st.w = (_Float16)0.f;
  fq[(size_t)bt8 * (size_t)(NFACE * 8) + (size_t)f * 8 + bi] = st;
}

// K4: face_color only — vn gather + rotate-normal + SH lighting. No position work.
#define FI_CH2 1116   // ceil(NVERT/32)
__global__ __launch_bounds__(256) void k_final(const u16* __restrict__ texT, const h4* __restrict__ fq,
                                               const int* __restrict__ pbuf, const float* __restrict__ mpad,
                                               const float* __restrict__ G, float* __restrict__ out) {
  __shared__ float scol[8][100];   // [bi][voff*3+c], pad 96->100
  int g = blockIdx.x;
  int xcd = g & 7, sgi = g >> 3;
  int btg = sgi / FI_CH2, chunk = sgi - btg * FI_CH2;
  int bt8 = btg * 8 + xcd;
  int t = threadIdx.x;
  int bi = t & 7, voff = t >> 3;
  int v0 = chunk * 32;
  int v = v0 + voff;
  int vc = v < NVERT ? v : NVERT - 1;
  bool valid = v < NVERT;
  int b = bt8 * 8 + bi;
  i4 p0 = *(const i4*)(pbuf + (size_t)vc * 8);
  i4 p1 = *(const i4*)(pbuf + (size_t)vc * 8 + 4);
  int idx[8] = {p0.x, p0.y, p0.z, p0.w, p1.x, p1.y, p1.z, p1.w};
  const h4* fb = fq + (size_t)bt8 * (size_t)(NFACE * 8);
  float vx = 0.f, vy = 0.f, vz = 0.f;
#pragma unroll
  for (int i = 0; i < 8; i++) {
    int id = idx[i] - 1;               // in [0, NFACE]; NFACE == zero contribution
    if (id < NFACE) {
      h4 q = fb[(size_t)id * 8 + bi];
      vx += (float)q.x; vy += (float)q.y; vz += (float)q.z;
    }
  }
  float n2 = vx * vx + vy * vy + vz * vz;
  float inv = rsqrtf(fmaxf(n2, 1e-30f));
  vx *= inv; vy *= inv; vz *= inv;
  const float* mp = mpad + b * 12;
  f4 m0 = *(const f4*)mp;
  f4 m1 = *(const f4*)(mp + 4);
  float m8 = mp[8];
  float nx = vx * m0.x + vy * m0.y + vz * m0.z;
  float ny = vx * m0.w + vy * m1.x + vz * m1.y;
  float nz = vx * m1.z + vy * m1.w + vz * m8;
  // SH lighting
  const float kc1 = 1.7724539f;             // a1*c1 = sqrt(pi)
  const float kc2 = 2.4270324f;             // a2*c2
  const float kd0 = 0.28867513f;            // 0.5/sqrt(3)
  float Y[9];
  Y[0] = 0.8862269f;                        // a0*c0
  Y[1] = -kc1 * ny;
  Y[2] = kc1 * nz;
  Y[3] = -kc1 * nx;
  Y[4] = kc2 * nx * ny;
  Y[5] = -kc2 * ny * nz;
  Y[6] = kc2 * kd0 * (3.f * nz * nz - 1.f);
  Y[7] = -kc2 * nx * nz;
  Y[8] = kc2 * 0.5f * (nx * nx - ny * ny);
  const float* gg = G + b * 27;
  float gv[28];
#pragma unroll
  for (int q = 0; q < 7; q++) {
    f4 g4 = ld4u(gg + q * 4);
    gv[q * 4] = g4.x; gv[q * 4 + 1] = g4.y; gv[q * 4 + 2] = g4.z; gv[q * 4 + 3] = g4.w;
  }
  const u16* tp = texT + (size_t)bt8 * (size_t)(NV3 * 8) + (size_t)vc * 24 + bi;
  if (valid) {
#pragma unroll
    for (int d = 0; d < 3; d++) {
      float L = 0.f;
#pragma unroll
      for (int cc = 0; cc < 9; cc++) L += Y[cc] * gv[cc * 3 + d];
      float tx = b2f(__builtin_nontemporal_load(tp + d * 8));
      scol[bi][voff * 3 + d] = tx * L;
    }
  }
  __syncthreads();
  int nvv = NVERT - v0;
  int lim = (nvv < 32 ? nvv : 32) * 3;
  size_t base = (size_t)(bt8 * 8) * NV3 + (size_t)v0 * 3;
#pragma unroll
  for (int it = 0; it < 3; it++) {
    int l = it * 256 + t;                  // 0..767
    int b2 = l / 96, e = l - b2 * 96;
    if (e < lim) {
      size_t o = base + (size_t)b2 * NV3 + e;
      __builtin_nontemporal_store(scol[b2][e], out + o);
    }
  }
}

// K5: landmarks — recompute shape_t at 68 kp verts from shpT, project (f32 out).
__global__ __launch_bounds__(128) void k_lms(const float* __restrict__ shpT, const int* __restrict__ kp,
                                             const float* __restrict__ mpad, float* __restrict__ out) {
  int t = threadIdx.x;
  int b = blockIdx.x;
  if (t >= 68) return;
  int v = kp[t];
  const float* sl = shpT + (size_t)(b >> 3) * (size_t)(NV3 * 8) + (size_t)v * 24 + (b & 7);
  float sx = sl[0], sy = sl[8], sz = sl[16];
  const float* mp = mpad + b * 12;
  f4 m0 = *(const f4*)mp;
  f4 m1 = *(const f4*)(mp + 4);
  f4 m2 = *(const f4*)(mp + 8);
  float ox = sx * m0.x + sy * m0.y + sz * m0.z + m2.y;
  float oy = sx * m0.w + sy * m1.x + sz * m1.y + m2.z;
  float oz = sx * m1.z + sy * m1.w + sz * m2.x + m2.w;
  float w = 10.f - oz;                      // pts@[1,1,-1] + [0,0,10]
  float invw = 1.0f / w;
  float lx = 1015.f * ox * invw + 128.f;    // FOCAL*x/w + half
  float ly = 1015.f * oy * invw + 128.f;
  size_t o = LMS_BASE + ((size_t)b * 68 + t) * 2;
  out[o + 0] = lx;
  out[o + 1] = 256.f - ly;                  // IMG - y
}

extern "C" void kernel_launch(void* const* d_in, const int* in_sizes, int n_in,
                              void* d_out, int out_size, void* d_ws, size_t ws_size,
                              hipStream_t stream) {
  const float* coeff     = (const float*)d_in[0];
  const float* meanshape = (const float*)d_in[1];
  const float* idB       = (const float*)d_in[2];
  const float* exB       = (const float*)d_in[3];
  const float* meantex   = (const float*)d_in[4];
  const float* txB       = (const float*)d_in[5];
  const int* tri         = (const int*)d_in[6];
  const int* pbuf        = (const int*)d_in[7];
  const int* kp          = (const int*)d_in[8];
  float* out = (float*)d_out;
  char* ws = (char*)d_ws;
  float* shpT = (float*)(ws + SHAPE_OFF);
  u16* texT   = (u16*)(ws + TEX_OFF);
  h4* fq      = (h4*)(ws + FQ_OFF);
  u16* cpack  = (u16*)(ws + CPACK_OFF);
  float* mpad = (float*)(ws + MPAD_OFF);
  float* G    = (float*)(ws + GG_OFF);
  float* mean = (float*)(ws + MEAN_OFF);
  float* part = (float*)(ws + PART_OFF);

  k_mean<<<64, 256, 0, stream>>>(meanshape, part);
  k_params<<<1, 128, 0, stream>>>(coeff, cpack, mpad, G, part, mean);
  k_gemmS<<<SBLK, 256, 0, stream>>>(idB, exB, meanshape, cpack, mean, mpad, shpT, out);
  k_gemmT<<<1674, 256, 0, stream>>>(txB, meantex, cpack, texT);
  k_fn<<<8 * 2 * FN_CH2, 256, 0, stream>>>(shpT, tri, fq);
  k_final<<<8 * 2 * FI_CH2, 256, 0, stream>>>(texT, fq, pbuf, mpad, G, out);
  k_lms<<<128, 128, 0, stream>>>(shpT, kp, mpad, out);
}